// Round 4
// baseline (95.933 us; speedup 1.0000x reference)
//
#include <hip/hip_runtime.h>

// SPLoPA adapter: out[r][c] = weights[r][c] + sum_k pos[k, r/32, c/32] * w[k, r%32] * h[k, c%32]
// weights: 2048x2048 f32; pos: (64,64,64) f32; proto_w: (64,32,1); proto_h: (64,1,32)
//
// R4: each wave computes FOUR column-adjacent 32x32 tiles (j0..j0+3).
// Key fact: every tile (i,j) uses the SAME wv=w[k,a0..a0+3], hv=h[k,b0..b0+3];
// only the scalar pos[k,i,j] differs. So 2 ds_read_b128 per k serve 4 tiles
// (LDS/CU ~2.6us, off the critical path), pos is one uniform s_load_dwordx4/k.
// Budget/CU: VALU ~4.3us, HBM ~5.3us -> kernel ~6-7us, HBM/VALU co-bound.
// Grid: 1024 waves = 512 blocks x 128 thr (2 waves) -> 2 blocks/CU, 4 waves/CU.
// Latency hiding at 1 wave/SIMD comes from ILP: 16 indep FMA chains, unroll 8,
// all 16 weight float4s prefetched before the k-loop.

#define KDIM 64

__global__ __launch_bounds__(128) void splopa_kernel(
    const float* __restrict__ weights,
    const float* __restrict__ pos,
    const float* __restrict__ pw,    // (64,32): w[k*32 + a]
    const float* __restrict__ ph,    // (64,32): h[k*32 + b]
    float* __restrict__ out)
{
    __shared__ float w_lds[KDIM * 32];
    __shared__ float h_lds[KDIM * 32];

    const int tid = threadIdx.x;  // 0..127

    // Stage w,h into LDS: 2048 floats = 512 float4 each; 128 threads x 4 iters.
    {
        const float4* wg = (const float4*)pw;
        const float4* hg = (const float4*)ph;
        float4* wl = (float4*)w_lds;
        float4* hl = (float4*)h_lds;
        #pragma unroll
        for (int it = 0; it < 4; ++it) {
            wl[tid + 128 * it] = wg[tid + 128 * it];
            hl[tid + 128 * it] = hg[tid + 128 * it];
        }
    }

    const int wave = tid >> 6;   // 0..1
    const int lane = tid & 63;

    const int t  = (blockIdx.x << 1) + wave;  // tile-quad id 0..1023
    const int i  = t >> 4;                    // row tile 0..63
    const int j0 = (t & 15) << 2;             // left col tile 0,4,...,60
    int ij = (i << 6) + j0;
    ij = __builtin_amdgcn_readfirstlane(ij);  // wave-uniform -> s_load_dwordx4 of pos

    const int a0 = (lane >> 3) << 2;  // 0,4,...,28
    const int b0 = (lane & 7) << 2;   // 0,4,...,28

    const int row0 = (i << 5) + a0;
    const int col0 = (j0 << 5) + b0;
    const float* wptr = weights + (size_t)row0 * 2048 + col0;
    float*       optr = out     + (size_t)row0 * 2048 + col0;

    // Prefetch the 4x4 weights micro-tiles of all 4 tiles (tile tt at +32*tt cols).
    float4 wt[4][4];
    #pragma unroll
    for (int tt = 0; tt < 4; ++tt)
        #pragma unroll
        for (int r = 0; r < 4; ++r)
            wt[tt][r] = *(const float4*)(wptr + tt * 32 + (size_t)r * 2048);

    float4 acc[4][4];
    #pragma unroll
    for (int tt = 0; tt < 4; ++tt)
        #pragma unroll
        for (int r = 0; r < 4; ++r)
            acc[tt][r] = (float4){0.f, 0.f, 0.f, 0.f};

    __syncthreads();

    #pragma unroll 8
    for (int k = 0; k < KDIM; ++k) {
        const float4 pp = *(const float4*)&pos[(k << 12) + ij];   // s_load_dwordx4 (uniform)
        const float4 wv = *(const float4*)&w_lds[(k << 5) + a0];  // ds_read_b128, 8-way bcast
        const float4 hv = *(const float4*)&h_lds[(k << 5) + b0];  // ds_read_b128, 8-way bcast
        const float pk[4] = {pp.x, pp.y, pp.z, pp.w};

        #pragma unroll
        for (int tt = 0; tt < 4; ++tt) {
            const float t0 = pk[tt] * wv.x;
            const float t1 = pk[tt] * wv.y;
            const float t2 = pk[tt] * wv.z;
            const float t3 = pk[tt] * wv.w;
            acc[tt][0].x += t0 * hv.x; acc[tt][0].y += t0 * hv.y;
            acc[tt][0].z += t0 * hv.z; acc[tt][0].w += t0 * hv.w;
            acc[tt][1].x += t1 * hv.x; acc[tt][1].y += t1 * hv.y;
            acc[tt][1].z += t1 * hv.z; acc[tt][1].w += t1 * hv.w;
            acc[tt][2].x += t2 * hv.x; acc[tt][2].y += t2 * hv.y;
            acc[tt][2].z += t2 * hv.z; acc[tt][2].w += t2 * hv.w;
            acc[tt][3].x += t3 * hv.x; acc[tt][3].y += t3 * hv.y;
            acc[tt][3].z += t3 * hv.z; acc[tt][3].w += t3 * hv.w;
        }
    }

    #pragma unroll
    for (int tt = 0; tt < 4; ++tt) {
        #pragma unroll
        for (int r = 0; r < 4; ++r) {
            wt[tt][r].x += acc[tt][r].x;
            wt[tt][r].y += acc[tt][r].y;
            wt[tt][r].z += acc[tt][r].z;
            wt[tt][r].w += acc[tt][r].w;
            *(float4*)(optr + tt * 32 + (size_t)r * 2048) = wt[tt][r];
        }
    }
}

extern "C" void kernel_launch(void* const* d_in, const int* in_sizes, int n_in,
                              void* d_out, int out_size, void* d_ws, size_t ws_size,
                              hipStream_t stream) {
    const float* weights = (const float*)d_in[0];  // 2048*2048
    const float* pos     = (const float*)d_in[1];  // 64*64*64
    const float* pw      = (const float*)d_in[2];  // 64*32*1
    const float* ph      = (const float*)d_in[3];  // 64*1*32
    float* out = (float*)d_out;                    // 2048*2048

    splopa_kernel<<<512, 128, 0, stream>>>(weights, pos, pw, ph, out);
}